// Round 1
// baseline (352.659 us; speedup 1.0000x reference)
//
#include <hip/hip_runtime.h>
#include <stdint.h>

typedef short s16x8 __attribute__((ext_vector_type(8)));
typedef float f32x4 __attribute__((ext_vector_type(4)));

#define TT 256
#define CC 384
#define HH 64

__device__ __forceinline__ unsigned short f2bf(float f) {
  union { float f; uint32_t u; } v; v.f = f;
  return (unsigned short)((v.u + 0x7fffu + ((v.u >> 16) & 1u)) >> 16);
}

__global__ __launch_bounds__(256, 1) void attn_head_kernel(
    const float* __restrict__ inp,
    const float* __restrict__ Wv, const float* __restrict__ bv,
    const float* __restrict__ Wk, const float* __restrict__ bk,
    const float* __restrict__ Wq, const float* __restrict__ bq,
    float* __restrict__ out)
{
  // LDS: staging (pad +8 bf16 rows to kill bank conflicts), K/Q/V swizzled, P scratch
  __shared__ unsigned short inp_lds[256][40];   // 20480 B  inp chunk [256][32] bf16
  __shared__ unsigned short wt_lds[192][40];    // 15360 B  W^T chunk [192 n][32 k] bf16
  __shared__ unsigned short K_lds[256 * 64];    // 32768 B  K[t][h], byte ^= (t&7)<<4
  __shared__ unsigned short Q_lds[256 * 64];    // 32768 B  Q[s][h], same swizzle
  __shared__ unsigned short V_lds[64 * 256];    // 32768 B  V^T[h][s], byte ^= (h&7)<<4
  __shared__ unsigned short P_lds[4][16][40];   //  5120 B  per-wave P tile [16 t][32 s]

  const int b    = blockIdx.x;
  const int tid  = threadIdx.x;
  const int wave = tid >> 6;
  const int lane = tid & 63;
  const int l15  = lane & 15;
  const int lg   = lane >> 4;

  const float* inp_b = inp + (size_t)b * TT * CC;

  // ---------------- Phase 1: KQV projection (cols 0..63 K, 64..127 Q, 128..191 V)
  f32x4 acc[4][12];
#pragma unroll
  for (int mf = 0; mf < 4; ++mf)
#pragma unroll
    for (int nf = 0; nf < 12; ++nf)
      acc[mf][nf] = (f32x4){0.f, 0.f, 0.f, 0.f};

  for (int k0 = 0; k0 < CC; k0 += 32) {
    __syncthreads();
    // stage inp chunk [256 t][32 k] fp32 -> bf16 (coalesced float4, 8/thread)
#pragma unroll
    for (int it = 0; it < 8; ++it) {
      int idx = tid + it * 256;
      int row = idx >> 3, c4 = idx & 7;
      float4 v = *(const float4*)(inp_b + row * CC + k0 + c4 * 4);
      unsigned short* d = &inp_lds[row][c4 * 4];
      d[0] = f2bf(v.x); d[1] = f2bf(v.y); d[2] = f2bf(v.z); d[3] = f2bf(v.w);
    }
    // stage weight chunks transposed into wt_lds[n][k]
#pragma unroll
    for (int m = 0; m < 3; ++m) {
      const float* W = (m == 0) ? Wk : (m == 1 ? Wq : Wv);
#pragma unroll
      for (int it = 0; it < 2; ++it) {
        int idx = tid + it * 256;          // 0..511 over [32 k][16 float4]
        int kk = idx >> 4, c4 = idx & 15;
        float4 v = *(const float4*)(W + (k0 + kk) * HH + c4 * 4);
        int nb = m * 64 + c4 * 4;
        wt_lds[nb + 0][kk] = f2bf(v.x);
        wt_lds[nb + 1][kk] = f2bf(v.y);
        wt_lds[nb + 2][kk] = f2bf(v.z);
        wt_lds[nb + 3][kk] = f2bf(v.w);
      }
    }
    __syncthreads();
    const int t0base = wave * 64;
    s16x8 bb[12];
#pragma unroll
    for (int nf = 0; nf < 12; ++nf)
      bb[nf] = *(const s16x8*)&wt_lds[nf * 16 + l15][lg * 8];
#pragma unroll
    for (int mf = 0; mf < 4; ++mf) {
      s16x8 a = *(const s16x8*)&inp_lds[t0base + mf * 16 + l15][lg * 8];
#pragma unroll
      for (int nf = 0; nf < 12; ++nf)
        acc[mf][nf] = __builtin_amdgcn_mfma_f32_16x16x32_bf16(a, bb[nf], acc[mf][nf], 0, 0, 0);
    }
  }

  // bias add, fold scale into K, convert to bf16, scatter into swizzled K/Q/V LDS
  {
    const float scale = 0.05103103630798287f;  // 384^-0.5 (embed dim per reference)
    const int t0base = wave * 64;
    char* Kb = (char*)K_lds; char* Qb = (char*)Q_lds; char* Vb = (char*)V_lds;
#pragma unroll
    for (int nf = 0; nf < 12; ++nf) {
      int n = nf * 16 + l15;
      float bias = (n < 64) ? bk[n] : (n < 128 ? bq[n - 64] : bv[n - 128]);
#pragma unroll
      for (int mf = 0; mf < 4; ++mf) {
#pragma unroll
        for (int r = 0; r < 4; ++r) {
          int t = t0base + mf * 16 + lg * 4 + r;   // D layout: row=(l>>4)*4+r, col=l&15
          float x = acc[mf][nf][r] + bias;
          if (n < 64) {
            int off = t * 128 + ((n * 2) ^ ((t & 7) << 4));
            *(unsigned short*)(Kb + off) = f2bf(x * scale);
          } else if (n < 128) {
            int nn = n - 64;
            int off = t * 128 + ((nn * 2) ^ ((t & 7) << 4));
            *(unsigned short*)(Qb + off) = f2bf(x);
          } else {
            int nn = n - 128;
            int off = nn * 512 + ((t * 2) ^ ((nn & 7) << 4));
            *(unsigned short*)(Vb + off) = f2bf(x);
          }
        }
      }
    }
  }
  __syncthreads();

  // ---------------- Phase 2: causal attention, per-wave independent (no barriers)
  const char* Kb = (const char*)K_lds;
  const char* Qb = (const char*)Q_lds;
  const char* Vb = (const char*)V_lds;

  for (int ti = 0; ti < 4; ++ti) {
    const int tf = ((ti & 1) ? (7 - wave) : wave) + 8 * (ti >> 1);  // balanced causal work
    const int t0 = tf * 16;
    float m[4], lsum[4];
    f32x4 O[4];
#pragma unroll
    for (int r = 0; r < 4; ++r) { m[r] = -1e30f; lsum[r] = 0.f; }
#pragma unroll
    for (int nf = 0; nf < 4; ++nf) O[nf] = (f32x4){0.f, 0.f, 0.f, 0.f};

    const int trow = t0 + l15;
    const int swzT = (trow & 7) << 4;

    for (int s0 = 0; s0 < t0 + 16; s0 += 32) {
      f32x4 Sa = {0.f,0.f,0.f,0.f}, Sb = {0.f,0.f,0.f,0.f};
      const int srow = s0 + l15;
      const int swzS = (srow & 7) << 4;
#pragma unroll
      for (int kk = 0; kk < 2; ++kk) {
        int hb = (kk * 32 + lg * 8) * 2;
        s16x8 a  = *(const s16x8*)(Kb + trow * 128 + (hb ^ swzT));
        s16x8 q0 = *(const s16x8*)(Qb + srow * 128 + (hb ^ swzS));
        s16x8 q1 = *(const s16x8*)(Qb + (srow + 16) * 128 + (hb ^ swzS));
        Sa = __builtin_amdgcn_mfma_f32_16x16x32_bf16(a, q0, Sa, 0, 0, 0);
        Sb = __builtin_amdgcn_mfma_f32_16x16x32_bf16(a, q1, Sb, 0, 0, 0);
      }
      // online softmax: rows t = t0+lg*4+r, cols s = s0+l15 (+16)
      float alpha[4], pa[4], pb[4];
#pragma unroll
      for (int r = 0; r < 4; ++r) {
        int t = t0 + lg * 4 + r;
        int sA = s0 + l15;
        float xa = (sA      <= t) ? Sa[r] : -1e30f;
        float xb = (sA + 16 <= t) ? Sb[r] : -1e30f;
        float mx = fmaxf(xa, xb);
#pragma unroll
        for (int d = 1; d < 16; d <<= 1) mx = fmaxf(mx, __shfl_xor(mx, d, 64));
        float mn = fmaxf(m[r], mx);
        alpha[r] = __expf(m[r] - mn);
        m[r] = mn;
        pa[r] = __expf(xa - mn);
        pb[r] = __expf(xb - mn);
        float rs = pa[r] + pb[r];
#pragma unroll
        for (int d = 1; d < 16; d <<= 1) rs += __shfl_xor(rs, d, 64);
        lsum[r] = lsum[r] * alpha[r] + rs;
      }
#pragma unroll
      for (int nf = 0; nf < 4; ++nf)
#pragma unroll
        for (int r = 0; r < 4; ++r) O[nf][r] *= alpha[r];
      // P tile -> wave-private LDS (D layout), fence, reload as A-fragment
#pragma unroll
      for (int r = 0; r < 4; ++r) {
        int prow = lg * 4 + r;
        P_lds[wave][prow][l15]      = f2bf(pa[r]);
        P_lds[wave][prow][l15 + 16] = f2bf(pb[r]);
      }
      asm volatile("s_waitcnt lgkmcnt(0)" ::: "memory");
      s16x8 pfrag = *(const s16x8*)&P_lds[wave][l15][lg * 8];
#pragma unroll
      for (int nf = 0; nf < 4; ++nf) {
        int h = nf * 16 + l15;
        int sbyte = (s0 + lg * 8) * 2;
        s16x8 vb = *(const s16x8*)(Vb + h * 512 + (sbyte ^ ((h & 7) << 4)));
        O[nf] = __builtin_amdgcn_mfma_f32_16x16x32_bf16(pfrag, vb, O[nf], 0, 0, 0);
      }
    }
    // epilogue: divide by softmax denom, coalesced f32 stores
    float* outb = out + ((size_t)b * TT + t0) * HH;
#pragma unroll
    for (int r = 0; r < 4; ++r) {
      float inv = 1.0f / lsum[r];
#pragma unroll
      for (int nf = 0; nf < 4; ++nf)
        outb[(lg * 4 + r) * HH + nf * 16 + l15] = O[nf][r] * inv;
    }
  }
}

extern "C" void kernel_launch(void* const* d_in, const int* in_sizes, int n_in,
                              void* d_out, int out_size, void* d_ws, size_t ws_size,
                              hipStream_t stream) {
  (void)n_in; (void)out_size; (void)d_ws; (void)ws_size;
  const float* inp = (const float*)d_in[0];
  const float* Wv  = (const float*)d_in[1];
  const float* bv  = (const float*)d_in[2];
  const float* Wk  = (const float*)d_in[3];
  const float* bk  = (const float*)d_in[4];
  const float* Wq  = (const float*)d_in[5];
  const float* bq  = (const float*)d_in[6];
  float* out = (float*)d_out;
  const int B = in_sizes[0] / (TT * CC);   // 512
  attn_head_kernel<<<B, 256, 0, stream>>>(inp, Wv, bv, Wk, bk, Wq, bq, out);
}

// Round 2
// 324.261 us; speedup vs baseline: 1.0876x; 1.0876x over previous
//
#include <hip/hip_runtime.h>
#include <stdint.h>

typedef short s16x8 __attribute__((ext_vector_type(8)));
typedef float f32x4 __attribute__((ext_vector_type(4)));

#define TT 256
#define CC 384
#define HH 64

__device__ __forceinline__ unsigned short f2bf(float f) {
  union { float f; uint32_t u; } v; v.f = f;
  return (unsigned short)((v.u + 0x7fffu + ((v.u >> 16) & 1u)) >> 16);
}

__global__ __launch_bounds__(512, 2) void attn_head_kernel(
    const float* __restrict__ inp,
    const float* __restrict__ Wv, const float* __restrict__ bv,
    const float* __restrict__ Wk, const float* __restrict__ bk,
    const float* __restrict__ Wq, const float* __restrict__ bq,
    float* __restrict__ out)
{
  // LDS: staging (pad rows to 40 u16 = 80 B), K/Q/V swizzled, per-wave P scratch
  __shared__ unsigned short inp_lds[256][40];   // 20480 B  inp chunk [256 t][32 k] bf16
  __shared__ unsigned short wt_lds[192][40];    // 15360 B  W^T chunk [192 n][32 k] bf16
  __shared__ unsigned short K_lds[256 * 64];    // 32768 B  K[t][h], byte ^= (t&7)<<4
  __shared__ unsigned short Q_lds[256 * 64];    // 32768 B  Q[s][h], same swizzle
  __shared__ unsigned short V_lds[64 * 256];    // 32768 B  V^T[h][s], byte ^= (h&7)<<4
  __shared__ unsigned short P_lds[8][16][40];   // 10240 B  per-wave P tile [16 t][32 s]

  const int b    = blockIdx.x;
  const int tid  = threadIdx.x;
  const int wave = tid >> 6;     // 0..7
  const int lane = tid & 63;
  const int l15  = lane & 15;
  const int lg   = lane >> 4;

  const float* inp_b = inp + (size_t)b * TT * CC;

  // ---------------- Phase 1: KQV projection (cols 0..63 K, 64..127 Q, 128..191 V)
  f32x4 acc[2][12];
#pragma unroll
  for (int mf = 0; mf < 2; ++mf)
#pragma unroll
    for (int nf = 0; nf < 12; ++nf)
      acc[mf][nf] = (f32x4){0.f, 0.f, 0.f, 0.f};

  // register staging buffers (double-buffer vs LDS writes)
  float4 rin[4];
  float4 rw[3];
  const int wkk = tid >> 4;      // 0..31  (weight k within chunk)
  const int wc4 = tid & 15;      // 0..15  (weight float4 col)

  // prologue: load chunk 0
#pragma unroll
  for (int it = 0; it < 4; ++it) {
    int idx = tid + it * 512;
    int row = idx >> 3, c4 = idx & 7;
    rin[it] = *(const float4*)(inp_b + row * CC + 0 + c4 * 4);
  }
  rw[0] = *(const float4*)(Wk + wkk * HH + wc4 * 4);
  rw[1] = *(const float4*)(Wq + wkk * HH + wc4 * 4);
  rw[2] = *(const float4*)(Wv + wkk * HH + wc4 * 4);

  for (int c = 0; c < 12; ++c) {
    __syncthreads();   // previous chunk's fragment reads done; LDS reusable
    // store current regs -> LDS (convert to bf16)
#pragma unroll
    for (int it = 0; it < 4; ++it) {
      int idx = tid + it * 512;
      int row = idx >> 3, c4 = idx & 7;
      unsigned short* d = &inp_lds[row][c4 * 4];
      d[0] = f2bf(rin[it].x); d[1] = f2bf(rin[it].y);
      d[2] = f2bf(rin[it].z); d[3] = f2bf(rin[it].w);
    }
#pragma unroll
    for (int m = 0; m < 3; ++m) {
      int nb = m * 64 + wc4 * 4;
      wt_lds[nb + 0][wkk] = f2bf(rw[m].x);
      wt_lds[nb + 1][wkk] = f2bf(rw[m].y);
      wt_lds[nb + 2][wkk] = f2bf(rw[m].z);
      wt_lds[nb + 3][wkk] = f2bf(rw[m].w);
    }
    // issue next chunk's loads now; latency hides under barrier + MFMA below
    if (c + 1 < 12) {
      int k0 = (c + 1) * 32;
#pragma unroll
      for (int it = 0; it < 4; ++it) {
        int idx = tid + it * 512;
        int row = idx >> 3, c4 = idx & 7;
        rin[it] = *(const float4*)(inp_b + row * CC + k0 + c4 * 4);
      }
      rw[0] = *(const float4*)(Wk + (k0 + wkk) * HH + wc4 * 4);
      rw[1] = *(const float4*)(Wq + (k0 + wkk) * HH + wc4 * 4);
      rw[2] = *(const float4*)(Wv + (k0 + wkk) * HH + wc4 * 4);
    }
    __syncthreads();
    // fragments + MFMA: wave owns 32 t-rows
    const int t0base = wave * 32;
    s16x8 bb[12];
#pragma unroll
    for (int nf = 0; nf < 12; ++nf)
      bb[nf] = *(const s16x8*)&wt_lds[nf * 16 + l15][lg * 8];
#pragma unroll
    for (int mf = 0; mf < 2; ++mf) {
      s16x8 a = *(const s16x8*)&inp_lds[t0base + mf * 16 + l15][lg * 8];
#pragma unroll
      for (int nf = 0; nf < 12; ++nf)
        acc[mf][nf] = __builtin_amdgcn_mfma_f32_16x16x32_bf16(a, bb[nf], acc[mf][nf], 0, 0, 0);
    }
  }

  // bias add, fold scale into K, convert to bf16, scatter into swizzled K/Q/V LDS
  {
    const float scale = 0.05103103630798287f;  // 384^-0.5 (embed dim per reference)
    const int t0base = wave * 32;
    char* Kb = (char*)K_lds; char* Qb = (char*)Q_lds; char* Vb = (char*)V_lds;
#pragma unroll
    for (int nf = 0; nf < 12; ++nf) {
      int n = nf * 16 + l15;
      float bias = (n < 64) ? bk[n] : (n < 128 ? bq[n - 64] : bv[n - 128]);
#pragma unroll
      for (int mf = 0; mf < 2; ++mf) {
#pragma unroll
        for (int r = 0; r < 4; ++r) {
          int t = t0base + mf * 16 + lg * 4 + r;   // D layout: row=(l>>4)*4+r, col=l&15
          float x = acc[mf][nf][r] + bias;
          if (n < 64) {
            int off = t * 128 + ((n * 2) ^ ((t & 7) << 4));
            *(unsigned short*)(Kb + off) = f2bf(x * scale);
          } else if (n < 128) {
            int nn = n - 64;
            int off = t * 128 + ((nn * 2) ^ ((t & 7) << 4));
            *(unsigned short*)(Qb + off) = f2bf(x);
          } else {
            int nn = n - 128;
            int off = nn * 512 + ((t * 2) ^ ((nn & 7) << 4));
            *(unsigned short*)(Vb + off) = f2bf(x);
          }
        }
      }
    }
  }
  __syncthreads();

  // ---------------- Phase 2: causal attention, per-wave independent (no barriers)
  const char* Kb = (const char*)K_lds;
  const char* Qb = (const char*)Q_lds;
  const char* Vb = (const char*)V_lds;

  for (int ti = 0; ti < 2; ++ti) {
    const int tf = ti ? (15 - wave) : wave;   // balanced causal snake: (w+1)+(16-w)=17
    const int t0 = tf * 16;
    float m[4], lsum[4];
    f32x4 O[4];
#pragma unroll
    for (int r = 0; r < 4; ++r) { m[r] = -1e30f; lsum[r] = 0.f; }
#pragma unroll
    for (int nf = 0; nf < 4; ++nf) O[nf] = (f32x4){0.f, 0.f, 0.f, 0.f};

    const int trow = t0 + l15;
    const int swzT = (trow & 7) << 4;

    for (int s0 = 0; s0 < t0 + 16; s0 += 32) {
      f32x4 Sa = {0.f,0.f,0.f,0.f}, Sb = {0.f,0.f,0.f,0.f};
      const int srow = s0 + l15;
      const int swzS = (srow & 7) << 4;
#pragma unroll
      for (int kk = 0; kk < 2; ++kk) {
        int hb = (kk * 32 + lg * 8) * 2;
        s16x8 a  = *(const s16x8*)(Kb + trow * 128 + (hb ^ swzT));
        s16x8 q0 = *(const s16x8*)(Qb + srow * 128 + (hb ^ swzS));
        s16x8 q1 = *(const s16x8*)(Qb + (srow + 16) * 128 + (hb ^ swzS));
        Sa = __builtin_amdgcn_mfma_f32_16x16x32_bf16(a, q0, Sa, 0, 0, 0);
        Sb = __builtin_amdgcn_mfma_f32_16x16x32_bf16(a, q1, Sb, 0, 0, 0);
      }
      // online softmax: rows t = t0+lg*4+r, cols s = s0+l15 (+16)
      float alpha[4], pa[4], pb[4];
#pragma unroll
      for (int r = 0; r < 4; ++r) {
        int t = t0 + lg * 4 + r;
        int sA = s0 + l15;
        float xa = (sA      <= t) ? Sa[r] : -1e30f;
        float xb = (sA + 16 <= t) ? Sb[r] : -1e30f;
        float mx = fmaxf(xa, xb);
#pragma unroll
        for (int d = 1; d < 16; d <<= 1) mx = fmaxf(mx, __shfl_xor(mx, d, 64));
        float mn = fmaxf(m[r], mx);
        alpha[r] = __expf(m[r] - mn);
        m[r] = mn;
        pa[r] = __expf(xa - mn);
        pb[r] = __expf(xb - mn);
        float rs = pa[r] + pb[r];
#pragma unroll
        for (int d = 1; d < 16; d <<= 1) rs += __shfl_xor(rs, d, 64);
        lsum[r] = lsum[r] * alpha[r] + rs;
      }
#pragma unroll
      for (int nf = 0; nf < 4; ++nf)
#pragma unroll
        for (int r = 0; r < 4; ++r) O[nf][r] *= alpha[r];
      // P tile -> wave-private LDS (D layout), fence, reload as A-fragment
#pragma unroll
      for (int r = 0; r < 4; ++r) {
        int prow = lg * 4 + r;
        P_lds[wave][prow][l15]      = f2bf(pa[r]);
        P_lds[wave][prow][l15 + 16] = f2bf(pb[r]);
      }
      asm volatile("s_waitcnt lgkmcnt(0)" ::: "memory");
      __builtin_amdgcn_sched_barrier(0);
      s16x8 pfrag = *(const s16x8*)&P_lds[wave][l15][lg * 8];
#pragma unroll
      for (int nf = 0; nf < 4; ++nf) {
        int h = nf * 16 + l15;
        int sbyte = (s0 + lg * 8) * 2;
        s16x8 vb = *(const s16x8*)(Vb + h * 512 + (sbyte ^ ((h & 7) << 4)));
        O[nf] = __builtin_amdgcn_mfma_f32_16x16x32_bf16(pfrag, vb, O[nf], 0, 0, 0);
      }
    }
    // epilogue: divide by softmax denom, coalesced f32 stores
    float* outb = out + ((size_t)b * TT + t0) * HH;
#pragma unroll
    for (int r = 0; r < 4; ++r) {
      float inv = 1.0f / lsum[r];
#pragma unroll
      for (int nf = 0; nf < 4; ++nf)
        outb[(lg * 4 + r) * HH + nf * 16 + l15] = O[nf][r] * inv;
    }
  }
}

extern "C" void kernel_launch(void* const* d_in, const int* in_sizes, int n_in,
                              void* d_out, int out_size, void* d_ws, size_t ws_size,
                              hipStream_t stream) {
  (void)n_in; (void)out_size; (void)d_ws; (void)ws_size;
  const float* inp = (const float*)d_in[0];
  const float* Wv  = (const float*)d_in[1];
  const float* bv  = (const float*)d_in[2];
  const float* Wk  = (const float*)d_in[3];
  const float* bk  = (const float*)d_in[4];
  const float* Wq  = (const float*)d_in[5];
  const float* bq  = (const float*)d_in[6];
  float* out = (float*)d_out;
  const int B = in_sizes[0] / (TT * CC);   // 512
  attn_head_kernel<<<B, 512, 0, stream>>>(inp, Wv, bv, Wk, bk, Wq, bq, out);
}